// Round 3
// baseline (5776.519 us; speedup 1.0000x reference)
//
#include <hip/hip_runtime.h>
#include <hip/hip_bf16.h>

// All inputs/outputs are FLOAT32 per the reference (jnp.float32 throughout).

// ---------------------------------------------------------------------------
// Generic NT GEMM: out[n, m] (+)= sum_k A[n,k] * B[m,k]  (+ bias[m])
// A: fp32, row stride lda. B: fp32, row stride ldb, element stride bstride
// along k (7 for conv weight slices, 1 otherwise).
// CONV: row n decodes to (b = n>>8, t = n&255); reads A row (b, t+shift),
// zeros outside [0,256).
// Grid: (N/64, M/64), block 256. Tile 64x64, BK=16, 4x4 micro-tile.
// ---------------------------------------------------------------------------
template<bool CONV>
__global__ __launch_bounds__(256)
void gemm_nt(const float* __restrict__ A, const float* __restrict__ Bw,
             const float* __restrict__ bias, float* __restrict__ out,
             int Kd, int lda, int ldb, int bstride,
             int out_ld, int out_col0, int shift, int accum)
{
    __shared__ float As[16][68];   // [k][row], pad 68
    __shared__ float Bs[16][68];
    const int t  = threadIdx.x;
    const int lr = t >> 2;          // 0..63 row of tile
    const int lc = (t & 3) * 4;     // 0,4,8,12 k-offset
    const int ty = t >> 4, tx = t & 15;
    const int n0 = blockIdx.x * 64, o0 = blockIdx.y * 64;
    float acc[4][4] = {};

    for (int k0 = 0; k0 < Kd; k0 += 16) {
        {   // A tile
            int n = n0 + lr;
            bool valid = true;
            if (CONV) {
                int b = n >> 8, tt = n & 255, st = tt + shift;
                valid = (st >= 0) && (st < 256);
                n = (b << 8) + (valid ? st : 0);
            }
            const float* ap = A + (size_t)n * lda + k0 + lc;
            #pragma unroll
            for (int u = 0; u < 4; u++)
                As[lc + u][lr] = valid ? ap[u] : 0.0f;
        }
        {   // B tile
            const float* bp = Bw + (size_t)(o0 + lr) * ldb + (size_t)(k0 + lc) * bstride;
            #pragma unroll
            for (int u = 0; u < 4; u++)
                Bs[lc + u][lr] = bp[(size_t)u * bstride];
        }
        __syncthreads();
        #pragma unroll
        for (int kk = 0; kk < 16; kk++) {
            float a[4], b[4];
            #pragma unroll
            for (int u = 0; u < 4; u++) a[u] = As[kk][ty * 4 + u];
            #pragma unroll
            for (int u = 0; u < 4; u++) b[u] = Bs[kk][tx * 4 + u];
            #pragma unroll
            for (int i = 0; i < 4; i++)
                #pragma unroll
                for (int j = 0; j < 4; j++)
                    acc[i][j] += a[i] * b[j];
        }
        __syncthreads();
    }
    #pragma unroll
    for (int i = 0; i < 4; i++) {
        int n = n0 + ty * 4 + i;
        float* op = out + (size_t)n * out_ld + out_col0 + o0 + tx * 4;
        #pragma unroll
        for (int j = 0; j < 4; j++) {
            float v = acc[i][j];
            if (bias) v += bias[o0 + tx * 4 + j];
            if (accum) op[j] += v; else op[j] = v;
        }
    }
}

// ---------------------------------------------------------------------------
__global__ __launch_bounds__(256)
void init_ms(float* __restrict__ ms, const float* b0, const float* b1,
             const float* b2, const float* b3, const float* b4)
{
    size_t idx = (size_t)blockIdx.x * 256 + threadIdx.x;  // < 2048*5120
    int col = (int)(idx % 5120);
    const float* bs[5] = {b0, b1, b2, b3, b4};
    ms[idx] = bs[col >> 10][col & 1023];
}

// ---------------------------------------------------------------------------
// LayerNorm (eps 1e-5, biased var) + exact GELU, in place on z rows of 1024.
// ---------------------------------------------------------------------------
__global__ __launch_bounds__(256)
void ln_gelu(float* __restrict__ z, const float* __restrict__ g,
             const float* __restrict__ b)
{
    __shared__ float r1[256], r2[256];
    const int n = blockIdx.x, t = threadIdx.x;
    float* row = z + (size_t)n * 1024;
    float x[4], s = 0.f, s2 = 0.f;
    #pragma unroll
    for (int u = 0; u < 4; u++) {
        x[u] = row[t + u * 256];
        s += x[u]; s2 += x[u] * x[u];
    }
    r1[t] = s; r2[t] = s2;
    __syncthreads();
    for (int off = 128; off > 0; off >>= 1) {
        if (t < off) { r1[t] += r1[t + off]; r2[t] += r2[t + off]; }
        __syncthreads();
    }
    const float mu  = r1[0] * (1.0f / 1024.0f);
    const float var = r2[0] * (1.0f / 1024.0f) - mu * mu;
    const float rstd = rsqrtf(var + 1e-5f);
    #pragma unroll
    for (int u = 0; u < 4; u++) {
        int c = t + u * 256;
        float y = (x[u] - mu) * rstd * g[c] + b[c];
        row[c] = 0.5f * y * (1.0f + erff(y * 0.70710678118654752f));
    }
}

// ---------------------------------------------------------------------------
// MHA core: per (b, h, 32-row i-tile): scores = qK^T/8, softmax, ctx = A V.
// ---------------------------------------------------------------------------
__global__ __launch_bounds__(256)
void attn_kernel(const float* __restrict__ q, const float* __restrict__ k,
                 const float* __restrict__ v, float* __restrict__ ctx)
{
    const int it = blockIdx.x, h = blockIdx.y, bb = blockIdx.z;
    const int i0 = it * 32;
    const size_t base = (size_t)bb * 256 * 1024 + h * 64;
    __shared__ float qs[32][64];
    __shared__ float ks[32][64];
    __shared__ float sc[32][257];
    const int t = threadIdx.x;

    for (int idx = t; idx < 32 * 64; idx += 256) {
        int r = idx >> 6, c = idx & 63;
        qs[r][c] = q[base + (size_t)(i0 + r) * 1024 + c];
    }
    __syncthreads();
    for (int jt = 0; jt < 8; jt++) {
        for (int idx = t; idx < 32 * 64; idx += 256) {
            int r = idx >> 6, c = idx & 63;
            ks[r][c] = k[base + (size_t)(jt * 32 + r) * 1024 + c];
        }
        __syncthreads();
        #pragma unroll
        for (int u = 0; u < 4; u++) {
            int p = t * 4 + u;            // 0..1023
            int i = p >> 5, j = p & 31;
            float s = 0.f;
            #pragma unroll 8
            for (int d = 0; d < 64; d++) s += qs[i][d] * ks[j][d];
            sc[i][jt * 32 + j] = s * 0.125f;
        }
        __syncthreads();
    }
    if (t < 32) {                          // row softmax
        float m = -1e30f;
        for (int j = 0; j < 256; j++) m = fmaxf(m, sc[t][j]);
        float l = 0.f;
        for (int j = 0; j < 256; j++) { float p = expf(sc[t][j] - m); sc[t][j] = p; l += p; }
        float inv = 1.0f / l;
        for (int j = 0; j < 256; j++) sc[t][j] *= inv;
    }
    __syncthreads();
    const int d = t & 63, ig = t >> 6;     // 4 i-groups
    float acc[8] = {};
    for (int j = 0; j < 256; j++) {
        float vv = v[base + (size_t)j * 1024 + d];
        #pragma unroll
        for (int u = 0; u < 8; u++) acc[u] += sc[ig + u * 4][j] * vv;
    }
    #pragma unroll
    for (int u = 0; u < 8; u++)
        ctx[base + (size_t)(i0 + ig + u * 4) * 1024 + d] = acc[u];
}

// ---------------------------------------------------------------------------
// GAT logits: e1[n,h] = hg[n,h,:].a1, e2 likewise.
// ---------------------------------------------------------------------------
__global__ __launch_bounds__(256)
void gat_e(const float* __restrict__ hg, const float* __restrict__ a1,
           const float* __restrict__ a2, float* __restrict__ e1,
           float* __restrict__ e2)
{
    int id = blockIdx.x * 256 + threadIdx.x;  // < 16384
    int n = id >> 3, h = id & 7;
    const float* hr = hg + (size_t)n * 1024 + h * 128;
    float s1 = 0.f, s2 = 0.f;
    for (int d = 0; d < 128; d++) {
        float x = hr[d];
        s1 += x * a1[d];
        s2 += x * a2[d];
    }
    e1[id] = s1; e2[id] = s2;
}

// ---------------------------------------------------------------------------
// GAT aggregate per (32-row i-tile, head h): softmax_j(lrelu(e1[i]+e2[j]))
// weighted sum of hg[j,h,:], then ELU + residual -> fp32 out.
// ---------------------------------------------------------------------------
__global__ __launch_bounds__(256)
void gat_agg(const float* __restrict__ hg, const float* __restrict__ e1,
             const float* __restrict__ e2, const float* __restrict__ feat,
             float* __restrict__ out)
{
    const int ib = blockIdx.x, h = blockIdx.y;
    const int i0 = ib * 32;
    __shared__ float e2s[2048];
    __shared__ float e1s[32], mS[32], lS[32];
    __shared__ float hgs[32][128];
    __shared__ float wt[32][33];     // [j_local][i_local]
    __shared__ float pm[256], pl[256];
    const int t = threadIdx.x;

    for (int idx = t; idx < 2048; idx += 256) e2s[idx] = e2[idx * 8 + h];
    if (t < 32) e1s[t] = e1[(i0 + t) * 8 + h];
    __syncthreads();

    // pass 1: online max/denominator per row i
    {
        int il = t & 31, jt = t >> 5;           // 8 j-groups
        float ev = e1s[il];
        float m = -1e30f, l = 0.f;
        for (int j = jt; j < 2048; j += 8) {
            float x = ev + e2s[j];
            x = (x >= 0.f) ? x : 0.2f * x;      // leaky_relu 0.2
            if (x > m) { l = l * expf(m - x) + 1.0f; m = x; }
            else       { l += expf(x - m); }
        }
        pm[t] = m; pl[t] = l;
        __syncthreads();
        if (t < 32) {
            float M = pm[t], L = pl[t];
            for (int g2 = 1; g2 < 8; g2++) {
                float m2 = pm[g2 * 32 + t], l2 = pl[g2 * 32 + t];
                if (m2 > M) { L = L * expf(M - m2) + l2; M = m2; }
                else        { L += l2 * expf(m2 - M); }
            }
            mS[t] = M; lS[t] = L;
        }
        __syncthreads();
    }

    // pass 2: weighted aggregation, 4x4 micro-tile per thread
    const int ti = t >> 5;          // i base = ti*4  (8 groups)
    const int td = t & 31;          // d base = td*4
    float acc[4][4] = {};
    for (int j0 = 0; j0 < 2048; j0 += 32) {
        for (int idx = t; idx < 4096; idx += 256) {
            int r = idx >> 7, c = idx & 127;
            hgs[r][c] = hg[(size_t)(j0 + r) * 1024 + h * 128 + c];
        }
        #pragma unroll
        for (int u = 0; u < 4; u++) {
            int idx = t * 4 + u;            // 0..1023
            int jl = idx >> 5, il = idx & 31;
            float x = e1s[il] + e2s[j0 + jl];
            x = (x >= 0.f) ? x : 0.2f * x;
            wt[jl][il] = expf(x - mS[il]);
        }
        __syncthreads();
        for (int jl = 0; jl < 32; jl++) {
            float w[4], hv[4];
            #pragma unroll
            for (int u = 0; u < 4; u++) w[u]  = wt[jl][ti * 4 + u];
            #pragma unroll
            for (int u = 0; u < 4; u++) hv[u] = hgs[jl][td * 4 + u];
            #pragma unroll
            for (int a = 0; a < 4; a++)
                #pragma unroll
                for (int c = 0; c < 4; c++)
                    acc[a][c] += w[a] * hv[c];
        }
        __syncthreads();
    }
    #pragma unroll
    for (int a = 0; a < 4; a++) {
        int i = i0 + ti * 4 + a;
        float inv = 1.0f / lS[ti * 4 + a];
        #pragma unroll
        for (int c = 0; c < 4; c++) {
            float vv = acc[a][c] * inv;
            vv = (vv > 0.f) ? vv : (expf(vv) - 1.0f);      // elu
            size_t off = (size_t)i * 1024 + h * 128 + td * 4 + c;
            out[off] = vv + feat[off];
        }
    }
}

// ---------------------------------------------------------------------------
extern "C" void kernel_launch(void* const* d_in, const int* in_sizes, int n_in,
                              void* d_out, int out_size, void* d_ws, size_t ws_size,
                              hipStream_t stream)
{
    const float* feat = (const float*)d_in[0];
    const float *cw[5], *cb[5];
    if (in_sizes[2] == 1024) {      // interleaved dict order (w0,b0,w1,b1,...)
        for (int i = 0; i < 5; i++) { cw[i] = (const float*)d_in[1 + 2*i]; cb[i] = (const float*)d_in[2 + 2*i]; }
    } else {                        // grouped (w0..w4, b0..b4)
        for (int i = 0; i < 5; i++) { cw[i] = (const float*)d_in[1 + i];   cb[i] = (const float*)d_in[6 + i]; }
    }
    const float* fp_w = (const float*)d_in[11];
    const float* fp_b = (const float*)d_in[12];
    const float* ln_g = (const float*)d_in[13];
    const float* ln_b = (const float*)d_in[14];
    const float* wq = (const float*)d_in[15]; const float* bq = (const float*)d_in[16];
    const float* wk = (const float*)d_in[17]; const float* bk = (const float*)d_in[18];
    const float* wv = (const float*)d_in[19]; const float* bv = (const float*)d_in[20];
    const float* wo = (const float*)d_in[21]; const float* bo = (const float*)d_in[22];
    const float* gat_w = (const float*)d_in[23]; const float* gat_b = (const float*)d_in[24];
    const float* ga1 = (const float*)d_in[25]; const float* ga2 = (const float*)d_in[26];
    float* outp = (float*)d_out;

    // Workspace (~50.5 MB):
    //   region A: ms (2048x5120 = 10.49M floats) — dead after fusion GEMM,
    //             reused as qb|kb|vb|ctx|att (5 x 2.097M = 10.49M exactly).
    //   z (2.097M) — dead after QKV GEMMs, reused as hgb.
    float* W   = (float*)d_ws;
    float* ms  = W;
    float* z   = W + (size_t)2048 * 5120;
    float* e1  = z + (size_t)2048 * 1024;
    float* e2  = e1 + 16384;
    float* qb  = ms;
    float* kb  = qb + (size_t)2048 * 1024;
    float* vb  = kb + (size_t)2048 * 1024;
    float* ctx = vb + (size_t)2048 * 1024;
    float* att = ctx + (size_t)2048 * 1024;
    float* hgb = z;

    const dim3 blk(256);
    const dim3 gemm_grid(32, 16);       // 2048/64 x 1024/64

    // 1) ms = conv biases, then 5 convs x 7 taps as shifted accumulate-GEMMs
    init_ms<<<dim3(40960), blk, 0, stream>>>(ms, cb[0], cb[1], cb[2], cb[3], cb[4]);
    const int dil[5] = {1, 2, 4, 8, 16};
    for (int i = 0; i < 5; i++)
        for (int kk = 0; kk < 7; kk++)
            gemm_nt<true><<<gemm_grid, blk, 0, stream>>>(
                feat, cw[i] + kk, nullptr, ms,
                1024, 1024, 7168, 7, 5120, i * 1024, (kk - 3) * dil[i], 1);

    // 2) fusion proj: z = ms @ fp_w^T + fp_b
    gemm_nt<false><<<gemm_grid, blk, 0, stream>>>(
        ms, fp_w, fp_b, z, 5120, 5120, 5120, 1, 1024, 0, 0, 0);

    // 3) LayerNorm + exact GELU (in place)
    ln_gelu<<<dim3(2048), blk, 0, stream>>>(z, ln_g, ln_b);

    // 4) q, k, v projections (write into reused region A)
    gemm_nt<false><<<gemm_grid, blk, 0, stream>>>(z, wq, bq, qb, 1024, 1024, 1024, 1, 1024, 0, 0, 0);
    gemm_nt<false><<<gemm_grid, blk, 0, stream>>>(z, wk, bk, kb, 1024, 1024, 1024, 1, 1024, 0, 0, 0);
    gemm_nt<false><<<gemm_grid, blk, 0, stream>>>(z, wv, bv, vb, 1024, 1024, 1024, 1, 1024, 0, 0, 0);

    // 5) attention core
    attn_kernel<<<dim3(8, 16, 8), blk, 0, stream>>>(qb, kb, vb, ctx);

    // 6) output projection
    gemm_nt<false><<<gemm_grid, blk, 0, stream>>>(ctx, wo, bo, att, 1024, 1024, 1024, 1, 1024, 0, 0, 0);

    // 7) GAT projection: hg = att @ gat_w^T + gat_b  (z is dead; hgb = z)
    gemm_nt<false><<<gemm_grid, blk, 0, stream>>>(att, gat_w, gat_b, hgb, 1024, 1024, 1024, 1, 1024, 0, 0, 0);

    // 8) GAT logits + softmax-aggregate + ELU + residual -> fp32 out
    gat_e<<<dim3(64), blk, 0, stream>>>(hgb, ga1, ga2, e1, e2);
    gat_agg<<<dim3(64, 8), blk, 0, stream>>>(hgb, e1, e2, feat, outp);
}

// Round 4
// 1376.411 us; speedup vs baseline: 4.1968x; 4.1968x over previous
//
#include <hip/hip_runtime.h>
#include <hip/hip_bf16.h>

typedef __bf16 bf16_t;
typedef bf16_t bf16x8 __attribute__((ext_vector_type(8)));
typedef bf16_t bf16x4v __attribute__((ext_vector_type(4)));
typedef float f32x4 __attribute__((ext_vector_type(4)));

// ---------------------------------------------------------------------------
// fp32 -> bf16 elementwise (n multiple of 4)
// ---------------------------------------------------------------------------
__global__ __launch_bounds__(256)
void cvt_f32_bf16(const float* __restrict__ in, bf16_t* __restrict__ out, int n4)
{
    int i = blockIdx.x * 256 + threadIdx.x;
    if (i < n4) {
        float4 v = ((const float4*)in)[i];
        bf16x4v o = { (bf16_t)v.x, (bf16_t)v.y, (bf16_t)v.z, (bf16_t)v.w };
        *(bf16x4v*)&out[i * 4] = o;
    }
}

// ---------------------------------------------------------------------------
// Reorder conv weights (O,C,7) fp32 -> bf16 planes [(i*7+kk)][o][c]
// ---------------------------------------------------------------------------
__global__ __launch_bounds__(256)
void reorder_convw(const float* w0, const float* w1, const float* w2,
                   const float* w3, const float* w4, bf16_t* __restrict__ out)
{
    int gid = blockIdx.x * 256 + threadIdx.x;       // < 5*1024*1024
    int i = gid >> 20, rem = gid & 1048575;
    int o = rem >> 10, c = rem & 1023;
    const float* ws[5] = {w0, w1, w2, w3, w4};
    const float* src = ws[i] + (size_t)o * 7168 + c * 7;
    #pragma unroll
    for (int kk = 0; kk < 7; kk++)
        out[((size_t)(i * 7 + kk) << 20) + (o << 10) + c] = (bf16_t)src[kk];
}

__global__ __launch_bounds__(256)
void gather_bias(const float* b0, const float* b1, const float* b2,
                 const float* b3, const float* b4, float* __restrict__ out)
{
    int idx = blockIdx.x * 256 + threadIdx.x;       // < 5120
    const float* bs[5] = {b0, b1, b2, b3, b4};
    out[idx] = bs[idx >> 10][idx & 1023];
}

// ---------------------------------------------------------------------------
// bf16 MFMA NT GEMM: out[n, m] = sum_k A[n,k]*B[m,k] + bias[oc0+m]
// Tile 128x128, BK=32, 4 waves (2x2 of 64x64), 16x16x32 MFMA.
// CONV: blockIdx.z = conv index; loops 7 taps with shifted A rows
// (t-dim shift (kk-3)<<i, zero outside [0,256)); B plane per tap.
// ---------------------------------------------------------------------------
template<bool CONV, bool OUT_BF16>
__global__ __launch_bounds__(256)
void mfma_gemm(const bf16_t* __restrict__ A, const bf16_t* __restrict__ Bw,
               const float* __restrict__ bias, void* __restrict__ outv,
               int Kd, int lda, int ldb, int ldo, int out_col0)
{
    __shared__ __align__(16) bf16_t As[128 * 40];   // [row][40] pad: 80B rows
    __shared__ __align__(16) bf16_t Bs[128 * 40];
    const int t = threadIdx.x;
    const int lane = t & 63, wave = t >> 6;
    const int wn = (wave & 1) * 64, wm = (wave >> 1) * 64;
    const int q = lane >> 4, lr = lane & 15;
    const int n0 = blockIdx.x * 128, m0 = blockIdx.y * 128;
    const int row_s = t >> 2, seg = t & 3;          // staging: 2 rows/thread

    f32x4 acc[4][4];
    #pragma unroll
    for (int a = 0; a < 4; a++)
        #pragma unroll
        for (int b = 0; b < 4; b++) acc[a][b] = (f32x4){0.f, 0.f, 0.f, 0.f};

    const int taps = CONV ? 7 : 1;
    const int conv_i = CONV ? blockIdx.z : 0;

    for (int kk = 0; kk < taps; kk++) {
        const bf16_t* Bp = CONV ? (Bw + ((size_t)(conv_i * 7 + kk) << 20)) : Bw;
        const int shift = CONV ? ((kk - 3) << conv_i) : 0;
        for (int k0 = 0; k0 < Kd; k0 += 32) {
            #pragma unroll
            for (int p = 0; p < 2; p++) {
                int r = row_s + p * 64;
                // A row (with conv temporal shift)
                int n = n0 + r;
                bf16x8 vA = {};
                if (CONV) {
                    int tg = (n & 255) + shift;
                    if ((unsigned)tg < 256u)
                        vA = *(const bf16x8*)(A + (size_t)((n & ~255) + tg) * lda + k0 + seg * 8);
                } else {
                    vA = *(const bf16x8*)(A + (size_t)n * lda + k0 + seg * 8);
                }
                *(bf16x8*)&As[r * 40 + seg * 8] = vA;
                // B row
                bf16x8 vB = *(const bf16x8*)(Bp + (size_t)(m0 + r) * ldb + k0 + seg * 8);
                *(bf16x8*)&Bs[r * 40 + seg * 8] = vB;
            }
            __syncthreads();
            bf16x8 af[4], bfv[4];
            #pragma unroll
            for (int f = 0; f < 4; f++) {
                af[f]  = *(bf16x8*)&As[(wn + f * 16 + lr) * 40 + q * 8];
                bfv[f] = *(bf16x8*)&Bs[(wm + f * 16 + lr) * 40 + q * 8];
            }
            #pragma unroll
            for (int fn = 0; fn < 4; fn++)
                #pragma unroll
                for (int fm = 0; fm < 4; fm++)
                    acc[fn][fm] = __builtin_amdgcn_mfma_f32_16x16x32_bf16(
                        af[fn], bfv[fm], acc[fn][fm], 0, 0, 0);
            __syncthreads();
        }
    }

    const int oc0 = CONV ? (conv_i << 10) : out_col0;
    #pragma unroll
    for (int fn = 0; fn < 4; fn++) {
        #pragma unroll
        for (int r = 0; r < 4; r++) {
            int n = n0 + wn + fn * 16 + q * 4 + r;
            #pragma unroll
            for (int fm = 0; fm < 4; fm++) {
                int m = m0 + wm + fm * 16 + lr;
                float v = acc[fn][fm][r];
                if (bias) v += bias[oc0 + m];
                if (OUT_BF16)
                    ((bf16_t*)outv)[(size_t)n * ldo + oc0 + m] = (bf16_t)v;
                else
                    ((float*)outv)[(size_t)n * ldo + oc0 + m] = v;
            }
        }
    }
}

// ---------------------------------------------------------------------------
// LayerNorm (eps 1e-5) + exact GELU, in place on z (fp32) + bf16 copy zb.
// ---------------------------------------------------------------------------
__global__ __launch_bounds__(256)
void ln_gelu(float* __restrict__ z, bf16_t* __restrict__ zb,
             const float* __restrict__ g, const float* __restrict__ b)
{
    __shared__ float r1[256], r2[256];
    const int n = blockIdx.x, t = threadIdx.x;
    float* row = z + (size_t)n * 1024;
    float x[4], s = 0.f, s2 = 0.f;
    #pragma unroll
    for (int u = 0; u < 4; u++) {
        x[u] = row[t + u * 256];
        s += x[u]; s2 += x[u] * x[u];
    }
    r1[t] = s; r2[t] = s2;
    __syncthreads();
    for (int off = 128; off > 0; off >>= 1) {
        if (t < off) { r1[t] += r1[t + off]; r2[t] += r2[t + off]; }
        __syncthreads();
    }
    const float mu  = r1[0] * (1.0f / 1024.0f);
    const float var = r2[0] * (1.0f / 1024.0f) - mu * mu;
    const float rstd = rsqrtf(var + 1e-5f);
    #pragma unroll
    for (int u = 0; u < 4; u++) {
        int c = t + u * 256;
        float y = (x[u] - mu) * rstd * g[c] + b[c];
        float gv = 0.5f * y * (1.0f + erff(y * 0.70710678118654752f));
        row[c] = gv;
        zb[(size_t)n * 1024 + c] = (bf16_t)gv;
    }
}

// ---------------------------------------------------------------------------
// MHA core (bf16 q/k/v in, bf16 ctx out), fp32 math.
// ---------------------------------------------------------------------------
__global__ __launch_bounds__(256)
void attn_kernel(const bf16_t* __restrict__ q, const bf16_t* __restrict__ k,
                 const bf16_t* __restrict__ v, bf16_t* __restrict__ ctx)
{
    const int it = blockIdx.x, h = blockIdx.y, bb = blockIdx.z;
    const int i0 = it * 32;
    const size_t base = (size_t)bb * 256 * 1024 + h * 64;
    __shared__ float qs[32][64];
    __shared__ float ks[32][64];
    __shared__ float sc[32][257];
    const int t = threadIdx.x;

    for (int idx = t; idx < 32 * 64; idx += 256) {
        int r = idx >> 6, c = idx & 63;
        qs[r][c] = (float)q[base + (size_t)(i0 + r) * 1024 + c];
    }
    __syncthreads();
    for (int jt = 0; jt < 8; jt++) {
        for (int idx = t; idx < 32 * 64; idx += 256) {
            int r = idx >> 6, c = idx & 63;
            ks[r][c] = (float)k[base + (size_t)(jt * 32 + r) * 1024 + c];
        }
        __syncthreads();
        #pragma unroll
        for (int u = 0; u < 4; u++) {
            int p = t * 4 + u;
            int i = p >> 5, j = p & 31;
            float s = 0.f;
            #pragma unroll 8
            for (int d = 0; d < 64; d++) s += qs[i][d] * ks[j][d];
            sc[i][jt * 32 + j] = s * 0.125f;
        }
        __syncthreads();
    }
    if (t < 32) {
        float m = -1e30f;
        for (int j = 0; j < 256; j++) m = fmaxf(m, sc[t][j]);
        float l = 0.f;
        for (int j = 0; j < 256; j++) { float p = expf(sc[t][j] - m); sc[t][j] = p; l += p; }
        float inv = 1.0f / l;
        for (int j = 0; j < 256; j++) sc[t][j] *= inv;
    }
    __syncthreads();
    const int d = t & 63, ig = t >> 6;
    float acc[8] = {};
    for (int j = 0; j < 256; j++) {
        float vv = (float)v[base + (size_t)j * 1024 + d];
        #pragma unroll
        for (int u = 0; u < 8; u++) acc[u] += sc[ig + u * 4][j] * vv;
    }
    #pragma unroll
    for (int u = 0; u < 8; u++)
        ctx[base + (size_t)(i0 + ig + u * 4) * 1024 + d] = (bf16_t)acc[u];
}

// ---------------------------------------------------------------------------
// GAT logits: e1[n,h] = hg[n,h,:].a1, e2 likewise. (hg fp32)
// ---------------------------------------------------------------------------
__global__ __launch_bounds__(256)
void gat_e(const float* __restrict__ hg, const float* __restrict__ a1,
           const float* __restrict__ a2, float* __restrict__ e1,
           float* __restrict__ e2)
{
    int id = blockIdx.x * 256 + threadIdx.x;  // < 16384
    int n = id >> 3, h = id & 7;
    const float* hr = hg + (size_t)n * 1024 + h * 128;
    float s1 = 0.f, s2 = 0.f;
    for (int d = 0; d < 128; d++) {
        float x = hr[d];
        s1 += x * a1[d];
        s2 += x * a2[d];
    }
    e1[id] = s1; e2[id] = s2;
}

// ---------------------------------------------------------------------------
// GAT aggregate + ELU + residual -> fp32 out.
// ---------------------------------------------------------------------------
__global__ __launch_bounds__(256)
void gat_agg(const float* __restrict__ hg, const float* __restrict__ e1,
             const float* __restrict__ e2, const float* __restrict__ feat,
             float* __restrict__ out)
{
    const int ib = blockIdx.x, h = blockIdx.y;
    const int i0 = ib * 32;
    __shared__ float e2s[2048];
    __shared__ float e1s[32], mS[32], lS[32];
    __shared__ float hgs[32][128];
    __shared__ float wt[32][33];
    __shared__ float pm[256], pl[256];
    const int t = threadIdx.x;

    for (int idx = t; idx < 2048; idx += 256) e2s[idx] = e2[idx * 8 + h];
    if (t < 32) e1s[t] = e1[(i0 + t) * 8 + h];
    __syncthreads();

    {   // pass 1: online max/denominator per row i
        int il = t & 31, jt = t >> 5;
        float ev = e1s[il];
        float m = -1e30f, l = 0.f;
        for (int j = jt; j < 2048; j += 8) {
            float x = ev + e2s[j];
            x = (x >= 0.f) ? x : 0.2f * x;
            if (x > m) { l = l * expf(m - x) + 1.0f; m = x; }
            else       { l += expf(x - m); }
        }
        pm[t] = m; pl[t] = l;
        __syncthreads();
        if (t < 32) {
            float M = pm[t], L = pl[t];
            for (int g2 = 1; g2 < 8; g2++) {
                float m2 = pm[g2 * 32 + t], l2 = pl[g2 * 32 + t];
                if (m2 > M) { L = L * expf(M - m2) + l2; M = m2; }
                else        { L += l2 * expf(m2 - M); }
            }
            mS[t] = M; lS[t] = L;
        }
        __syncthreads();
    }

    const int ti = t >> 5, td = t & 31;
    float acc[4][4] = {};
    for (int j0 = 0; j0 < 2048; j0 += 32) {
        for (int idx = t; idx < 4096; idx += 256) {
            int r = idx >> 7, c = idx & 127;
            hgs[r][c] = hg[(size_t)(j0 + r) * 1024 + h * 128 + c];
        }
        #pragma unroll
        for (int u = 0; u < 4; u++) {
            int idx = t * 4 + u;
            int jl = idx >> 5, il = idx & 31;
            float x = e1s[il] + e2s[j0 + jl];
            x = (x >= 0.f) ? x : 0.2f * x;
            wt[jl][il] = expf(x - mS[il]);
        }
        __syncthreads();
        for (int jl = 0; jl < 32; jl++) {
            float w[4], hv[4];
            #pragma unroll
            for (int u = 0; u < 4; u++) w[u]  = wt[jl][ti * 4 + u];
            #pragma unroll
            for (int u = 0; u < 4; u++) hv[u] = hgs[jl][td * 4 + u];
            #pragma unroll
            for (int a = 0; a < 4; a++)
                #pragma unroll
                for (int c = 0; c < 4; c++)
                    acc[a][c] += w[a] * hv[c];
        }
        __syncthreads();
    }
    #pragma unroll
    for (int a = 0; a < 4; a++) {
        int i = i0 + ti * 4 + a;
        float inv = 1.0f / lS[ti * 4 + a];
        #pragma unroll
        for (int c = 0; c < 4; c++) {
            float vv = acc[a][c] * inv;
            vv = (vv > 0.f) ? vv : (expf(vv) - 1.0f);
            size_t off = (size_t)i * 1024 + h * 128 + td * 4 + c;
            out[off] = vv + feat[off];
        }
    }
}

// ---------------------------------------------------------------------------
extern "C" void kernel_launch(void* const* d_in, const int* in_sizes, int n_in,
                              void* d_out, int out_size, void* d_ws, size_t ws_size,
                              hipStream_t stream)
{
    const float* feat = (const float*)d_in[0];
    const float *cw[5], *cb[5];
    if (in_sizes[2] == 1024) {
        for (int i = 0; i < 5; i++) { cw[i] = (const float*)d_in[1 + 2*i]; cb[i] = (const float*)d_in[2 + 2*i]; }
    } else {
        for (int i = 0; i < 5; i++) { cw[i] = (const float*)d_in[1 + i];   cb[i] = (const float*)d_in[6 + i]; }
    }
    const float* fp_w = (const float*)d_in[11];
    const float* fp_b = (const float*)d_in[12];
    const float* ln_g = (const float*)d_in[13];
    const float* ln_b = (const float*)d_in[14];
    const float* wq = (const float*)d_in[15]; const float* bq = (const float*)d_in[16];
    const float* wk = (const float*)d_in[17]; const float* bk = (const float*)d_in[18];
    const float* wv = (const float*)d_in[19]; const float* bv = (const float*)d_in[20];
    const float* wo = (const float*)d_in[21]; const float* bo = (const float*)d_in[22];
    const float* gat_w = (const float*)d_in[23]; const float* gat_b = (const float*)d_in[24];
    const float* ga1 = (const float*)d_in[25]; const float* ga2 = (const float*)d_in[26];
    float* outp = (float*)d_out;

    // ---- workspace layout (~118 MiB) ----
    char* wsb = (char*)d_ws;
    bf16_t* xb    = (bf16_t*)(wsb);                     //  4,194,304 (2M bf16)
    bf16_t* msb   = (bf16_t*)(wsb + 4194304);           // 20,971,520 (2048x5120)
    bf16_t* wcb   = (bf16_t*)(wsb + 25165824);          // 73,400,320 (35 planes)
    float*  zf    = (float*) (wsb + 98566144);          //  8,388,608
    bf16_t* zb    = (bf16_t*)(wsb + 106954752);         //  4,194,304
    bf16_t* qb    = (bf16_t*)(wsb + 111149056);         //  4,194,304
    bf16_t* kb    = (bf16_t*)(wsb + 115343360);         //  4,194,304
    bf16_t* vb    = (bf16_t*)(wsb + 119537664);         //  4,194,304
    float*  cball = (float*) (wsb + 123731968);         //     20,480
    float*  e1    = (float*) (wsb + 123752448);         //     65,536
    float*  e2    = (float*) (wsb + 123817984);         //     65,536
    // aliases (stream-ordered reuse):
    bf16_t* fpwb = wcb;                 // wcb dead after conv GEMM
    bf16_t* wqb  = wcb + 5242880;
    bf16_t* wkb  = wqb + 1048576;
    bf16_t* wvb  = wkb + 1048576;
    bf16_t* wob  = wvb + 1048576;
    bf16_t* gwb  = wob + 1048576;
    bf16_t* ctxb = qb;                  // attn reads its own q rows first
    bf16_t* attb = kb;                  // kb dead after attn
    float*  hgb  = zf;                  // zf dead after ln_gelu

    const dim3 blk(256);

    // 1) conversions + conv weight reorder
    cvt_f32_bf16<<<dim3(2048), blk, 0, stream>>>(feat, xb, 524288);
    reorder_convw<<<dim3(20480), blk, 0, stream>>>(cw[0], cw[1], cw[2], cw[3], cw[4], wcb);
    gather_bias<<<dim3(20), blk, 0, stream>>>(cb[0], cb[1], cb[2], cb[3], cb[4], cball);

    // 2) all 5 dilated convs, one MFMA launch -> msb (bf16, ld 5120)
    mfma_gemm<true, true><<<dim3(16, 8, 5), blk, 0, stream>>>(
        xb, wcb, cball, msb, 1024, 1024, 1024, 5120, 0);

    // 3) remaining weight conversions (reuse wcb region; stream-ordered)
    cvt_f32_bf16<<<dim3(5120), blk, 0, stream>>>(fp_w, fpwb, 1310720);
    cvt_f32_bf16<<<dim3(1024), blk, 0, stream>>>(wq, wqb, 262144);
    cvt_f32_bf16<<<dim3(1024), blk, 0, stream>>>(wk, wkb, 262144);
    cvt_f32_bf16<<<dim3(1024), blk, 0, stream>>>(wv, wvb, 262144);
    cvt_f32_bf16<<<dim3(1024), blk, 0, stream>>>(wo, wob, 262144);
    cvt_f32_bf16<<<dim3(1024), blk, 0, stream>>>(gat_w, gwb, 262144);

    // 4) fusion projection -> zf (fp32)
    mfma_gemm<false, false><<<dim3(16, 8), blk, 0, stream>>>(
        msb, fpwb, fp_b, zf, 5120, 5120, 5120, 1024, 0);

    // 5) LN + GELU -> zf (fp32) and zb (bf16)
    ln_gelu<<<dim3(2048), blk, 0, stream>>>(zf, zb, ln_g, ln_b);

    // 6) QKV projections -> bf16
    mfma_gemm<false, true><<<dim3(16, 8), blk, 0, stream>>>(zb, wqb, bq, qb, 1024, 1024, 1024, 1024, 0);
    mfma_gemm<false, true><<<dim3(16, 8), blk, 0, stream>>>(zb, wkb, bk, kb, 1024, 1024, 1024, 1024, 0);
    mfma_gemm<false, true><<<dim3(16, 8), blk, 0, stream>>>(zb, wvb, bv, vb, 1024, 1024, 1024, 1024, 0);

    // 7) attention -> ctxb (bf16)
    attn_kernel<<<dim3(8, 16, 8), blk, 0, stream>>>(qb, kb, vb, ctxb);

    // 8) output projection -> attb (bf16)
    mfma_gemm<false, true><<<dim3(16, 8), blk, 0, stream>>>(ctxb, wob, bo, attb, 1024, 1024, 1024, 1024, 0);

    // 9) GAT projection -> hgb (fp32)
    mfma_gemm<false, false><<<dim3(16, 8), blk, 0, stream>>>(attb, gwb, gat_b, hgb, 1024, 1024, 1024, 1024, 0);

    // 10) GAT logits + aggregate + ELU + residual -> fp32 out
    gat_e<<<dim3(64), blk, 0, stream>>>(hgb, ga1, ga2, e1, e2);
    gat_agg<<<dim3(64, 8), blk, 0, stream>>>(hgb, e1, e2, feat, outp);
}

// Round 5
// 1176.162 us; speedup vs baseline: 4.9113x; 1.1703x over previous
//
#include <hip/hip_runtime.h>
#include <hip/hip_bf16.h>

typedef __bf16 bf16_t;
typedef bf16_t bf16x8 __attribute__((ext_vector_type(8)));
typedef bf16_t bf16x4v __attribute__((ext_vector_type(4)));
typedef float f32x4 __attribute__((ext_vector_type(4)));

// ---------------------------------------------------------------------------
// fp32 -> bf16 elementwise (n multiple of 4)
// ---------------------------------------------------------------------------
__global__ __launch_bounds__(256)
void cvt_f32_bf16(const float* __restrict__ in, bf16_t* __restrict__ out, int n4)
{
    int i = blockIdx.x * 256 + threadIdx.x;
    if (i < n4) {
        float4 v = ((const float4*)in)[i];
        bf16x4v o = { (bf16_t)v.x, (bf16_t)v.y, (bf16_t)v.z, (bf16_t)v.w };
        *(bf16x4v*)&out[i * 4] = o;
    }
}

// ---------------------------------------------------------------------------
// Reorder conv weights (O,C,7) fp32 -> bf16 planes [(i*7+kk)][o][c]
// ---------------------------------------------------------------------------
__global__ __launch_bounds__(256)
void reorder_convw(const float* w0, const float* w1, const float* w2,
                   const float* w3, const float* w4, bf16_t* __restrict__ out)
{
    int gid = blockIdx.x * 256 + threadIdx.x;       // < 5*1024*1024
    int i = gid >> 20, rem = gid & 1048575;
    int o = rem >> 10, c = rem & 1023;
    const float* ws[5] = {w0, w1, w2, w3, w4};
    const float* src = ws[i] + (size_t)o * 7168 + c * 7;
    #pragma unroll
    for (int kk = 0; kk < 7; kk++)
        out[((size_t)(i * 7 + kk) << 20) + (o << 10) + c] = (bf16_t)src[kk];
}

__global__ __launch_bounds__(256)
void gather_bias(const float* b0, const float* b1, const float* b2,
                 const float* b3, const float* b4, float* __restrict__ out)
{
    int idx = blockIdx.x * 256 + threadIdx.x;       // < 5120
    const float* bs[5] = {b0, b1, b2, b3, b4};
    out[idx] = bs[idx >> 10][idx & 1023];
}

// ---------------------------------------------------------------------------
// bf16 MFMA NT GEMM: out[n, m] = sum_k A[n,k]*B[m,k] + bias[oc0+m]
// Tile 128x128, BK=32, 4 waves (2x2 of 64x64), 16x16x32 MFMA.
// CONV: blockIdx.z = conv index; loops 7 taps with shifted A rows.
// ---------------------------------------------------------------------------
template<bool CONV, bool OUT_BF16>
__global__ __launch_bounds__(256)
void mfma_gemm(const bf16_t* __restrict__ A, const bf16_t* __restrict__ Bw,
               const float* __restrict__ bias, void* __restrict__ outv,
               int Kd, int lda, int ldb, int ldo, int out_col0)
{
    __shared__ __align__(16) bf16_t As[128 * 40];
    __shared__ __align__(16) bf16_t Bs[128 * 40];
    const int t = threadIdx.x;
    const int lane = t & 63, wave = t >> 6;
    const int wn = (wave & 1) * 64, wm = (wave >> 1) * 64;
    const int q = lane >> 4, lr = lane & 15;
    const int n0 = blockIdx.x * 128, m0 = blockIdx.y * 128;
    const int row_s = t >> 2, seg = t & 3;

    f32x4 acc[4][4];
    #pragma unroll
    for (int a = 0; a < 4; a++)
        #pragma unroll
        for (int b = 0; b < 4; b++) acc[a][b] = (f32x4){0.f, 0.f, 0.f, 0.f};

    const int taps = CONV ? 7 : 1;
    const int conv_i = CONV ? blockIdx.z : 0;

    for (int kk = 0; kk < taps; kk++) {
        const bf16_t* Bp = CONV ? (Bw + ((size_t)(conv_i * 7 + kk) << 20)) : Bw;
        const int shift = CONV ? ((kk - 3) << conv_i) : 0;
        for (int k0 = 0; k0 < Kd; k0 += 32) {
            #pragma unroll
            for (int p = 0; p < 2; p++) {
                int r = row_s + p * 64;
                int n = n0 + r;
                bf16x8 vA = {};
                if (CONV) {
                    int tg = (n & 255) + shift;
                    if ((unsigned)tg < 256u)
                        vA = *(const bf16x8*)(A + (size_t)((n & ~255) + tg) * lda + k0 + seg * 8);
                } else {
                    vA = *(const bf16x8*)(A + (size_t)n * lda + k0 + seg * 8);
                }
                *(bf16x8*)&As[r * 40 + seg * 8] = vA;
                bf16x8 vB = *(const bf16x8*)(Bp + (size_t)(m0 + r) * ldb + k0 + seg * 8);
                *(bf16x8*)&Bs[r * 40 + seg * 8] = vB;
            }
            __syncthreads();
            bf16x8 af[4], bfv[4];
            #pragma unroll
            for (int f = 0; f < 4; f++) {
                af[f]  = *(bf16x8*)&As[(wn + f * 16 + lr) * 40 + q * 8];
                bfv[f] = *(bf16x8*)&Bs[(wm + f * 16 + lr) * 40 + q * 8];
            }
            #pragma unroll
            for (int fn = 0; fn < 4; fn++)
                #pragma unroll
                for (int fm = 0; fm < 4; fm++)
                    acc[fn][fm] = __builtin_amdgcn_mfma_f32_16x16x32_bf16(
                        af[fn], bfv[fm], acc[fn][fm], 0, 0, 0);
            __syncthreads();
        }
    }

    const int oc0 = CONV ? (conv_i << 10) : out_col0;
    #pragma unroll
    for (int fn = 0; fn < 4; fn++) {
        #pragma unroll
        for (int r = 0; r < 4; r++) {
            int n = n0 + wn + fn * 16 + q * 4 + r;
            #pragma unroll
            for (int fm = 0; fm < 4; fm++) {
                int m = m0 + wm + fm * 16 + lr;
                float v = acc[fn][fm][r];
                if (bias) v += bias[oc0 + m];
                if (OUT_BF16)
                    ((bf16_t*)outv)[(size_t)n * ldo + oc0 + m] = (bf16_t)v;
                else
                    ((float*)outv)[(size_t)n * ldo + oc0 + m] = v;
            }
        }
    }
}

// ---------------------------------------------------------------------------
// LayerNorm (eps 1e-5) + exact GELU, in place on z (fp32) + bf16 copy zb.
// ---------------------------------------------------------------------------
__global__ __launch_bounds__(256)
void ln_gelu(float* __restrict__ z, bf16_t* __restrict__ zb,
             const float* __restrict__ g, const float* __restrict__ b)
{
    __shared__ float r1[256], r2[256];
    const int n = blockIdx.x, t = threadIdx.x;
    float* row = z + (size_t)n * 1024;
    float x[4], s = 0.f, s2 = 0.f;
    #pragma unroll
    for (int u = 0; u < 4; u++) {
        x[u] = row[t + u * 256];
        s += x[u]; s2 += x[u] * x[u];
    }
    r1[t] = s; r2[t] = s2;
    __syncthreads();
    for (int off = 128; off > 0; off >>= 1) {
        if (t < off) { r1[t] += r1[t + off]; r2[t] += r2[t + off]; }
        __syncthreads();
    }
    const float mu  = r1[0] * (1.0f / 1024.0f);
    const float var = r2[0] * (1.0f / 1024.0f) - mu * mu;
    const float rstd = rsqrtf(var + 1e-5f);
    #pragma unroll
    for (int u = 0; u < 4; u++) {
        int c = t + u * 256;
        float y = (x[u] - mu) * rstd * g[c] + b[c];
        float gv = 0.5f * y * (1.0f + erff(y * 0.70710678118654752f));
        row[c] = gv;
        zb[(size_t)n * 1024 + c] = (bf16_t)gv;
    }
}

// ---------------------------------------------------------------------------
// MHA core (bf16 q/k/v in, bf16 ctx out), fp32 math.
// ---------------------------------------------------------------------------
__global__ __launch_bounds__(256)
void attn_kernel(const bf16_t* __restrict__ q, const bf16_t* __restrict__ k,
                 const bf16_t* __restrict__ v, bf16_t* __restrict__ ctx)
{
    const int it = blockIdx.x, h = blockIdx.y, bb = blockIdx.z;
    const int i0 = it * 32;
    const size_t base = (size_t)bb * 256 * 1024 + h * 64;
    __shared__ float qs[32][64];
    __shared__ float ks[32][64];
    __shared__ float sc[32][257];
    const int t = threadIdx.x;

    for (int idx = t; idx < 32 * 64; idx += 256) {
        int r = idx >> 6, c = idx & 63;
        qs[r][c] = (float)q[base + (size_t)(i0 + r) * 1024 + c];
    }
    __syncthreads();
    for (int jt = 0; jt < 8; jt++) {
        for (int idx = t; idx < 32 * 64; idx += 256) {
            int r = idx >> 6, c = idx & 63;
            ks[r][c] = (float)k[base + (size_t)(jt * 32 + r) * 1024 + c];
        }
        __syncthreads();
        #pragma unroll
        for (int u = 0; u < 4; u++) {
            int p = t * 4 + u;
            int i = p >> 5, j = p & 31;
            float s = 0.f;
            #pragma unroll 8
            for (int d = 0; d < 64; d++) s += qs[i][d] * ks[j][d];
            sc[i][jt * 32 + j] = s * 0.125f;
        }
        __syncthreads();
    }
    if (t < 32) {
        float m = -1e30f;
        for (int j = 0; j < 256; j++) m = fmaxf(m, sc[t][j]);
        float l = 0.f;
        for (int j = 0; j < 256; j++) { float p = expf(sc[t][j] - m); sc[t][j] = p; l += p; }
        float inv = 1.0f / l;
        for (int j = 0; j < 256; j++) sc[t][j] *= inv;
    }
    __syncthreads();
    const int d = t & 63, ig = t >> 6;
    float acc[8] = {};
    for (int j = 0; j < 256; j++) {
        float vv = (float)v[base + (size_t)j * 1024 + d];
        #pragma unroll
        for (int u = 0; u < 8; u++) acc[u] += sc[ig + u * 4][j] * vv;
    }
    #pragma unroll
    for (int u = 0; u < 8; u++)
        ctx[base + (size_t)(i0 + ig + u * 4) * 1024 + d] = (bf16_t)acc[u];
}

// ---------------------------------------------------------------------------
// GAT logits, TRANSPOSED out: e1t[h][n] = hg[n,h,:].a1 ; e2t likewise.
// id: h = id>>11, n = id & 2047 (coalesced writes).
// ---------------------------------------------------------------------------
__global__ __launch_bounds__(256)
void gat_e(const float* __restrict__ hg, const float* __restrict__ a1,
           const float* __restrict__ a2, float* __restrict__ e1t,
           float* __restrict__ e2t)
{
    int id = blockIdx.x * 256 + threadIdx.x;  // < 16384
    int h = id >> 11, n = id & 2047;
    const float* hr = hg + (size_t)n * 1024 + h * 128;
    float s1 = 0.f, s2 = 0.f;
    for (int d = 0; d < 128; d++) {
        float x = hr[d];
        s1 += x * a1[d];
        s2 += x * a2[d];
    }
    e1t[id] = s1; e2t[id] = s2;
}

// ---------------------------------------------------------------------------
// Transpose hg (2048 x 1024, fp32) -> hgT (1024 x 2048, bf16), 32x32 tiles.
// hgT row c = h*128+d, cols j.
// ---------------------------------------------------------------------------
__global__ __launch_bounds__(256)
void transpose_hg(const float* __restrict__ in, bf16_t* __restrict__ out)
{
    __shared__ float tile[32][33];
    const int t = threadIdx.x;
    const int j0 = blockIdx.x * 32, c0 = blockIdx.y * 32;
    {
        int jl = t >> 3, cl = (t & 7) * 4;
        float4 v = *(const float4*)(in + (size_t)(j0 + jl) * 1024 + c0 + cl);
        tile[jl][cl] = v.x; tile[jl][cl + 1] = v.y;
        tile[jl][cl + 2] = v.z; tile[jl][cl + 3] = v.w;
    }
    __syncthreads();
    {
        int cl = t >> 3, jl = (t & 7) * 4;
        bf16x4v o = { (bf16_t)tile[jl][cl], (bf16_t)tile[jl + 1][cl],
                      (bf16_t)tile[jl + 2][cl], (bf16_t)tile[jl + 3][cl] };
        *(bf16x4v*)&out[(size_t)(c0 + cl) * 2048 + j0 + jl] = o;
    }
}

// ---------------------------------------------------------------------------
// Fused GAT softmax-aggregate via MFMA.
// Block (it, h): 64 i-rows x 128 d. Pass 1: m_i, 1/l_i from LDS e2 row.
// Pass 2: per 128-j tile, P=exp(lrelu(e1+e2)-m) bf16 in LDS, MFMA vs hgT tile.
// Epilogue: *1/l, ELU, + feat -> fp32 out.  Grid (32, 8) x 256.
// ---------------------------------------------------------------------------
__global__ __launch_bounds__(256)
void gat_agg_mfma(const bf16_t* __restrict__ hgT, const float* __restrict__ e1t,
                  const float* __restrict__ e2t, const float* __restrict__ feat,
                  float* __restrict__ outp)
{
    const int it = blockIdx.x, h = blockIdx.y;
    const int i0 = it * 64;
    __shared__ float e2s[2048];
    __shared__ float e1s[64], mS[64], lSinv[64];
    __shared__ float pm[256], pl[256];
    __shared__ __align__(16) bf16_t Ps[64 * 136];
    __shared__ __align__(16) bf16_t Hs[128 * 136];
    const int t = threadIdx.x;
    const int lane = t & 63, wave = t >> 6;
    const int q = lane >> 4, lr = lane & 15;
    const int wm = wave * 32;

    for (int idx = t; idx < 2048; idx += 256) e2s[idx] = e2t[h * 2048 + idx];
    if (t < 64) e1s[t] = e1t[h * 2048 + i0 + t];
    __syncthreads();

    {   // pass 1: online max/denominator per row i (4 j-groups)
        int il = t & 63, jt = t >> 6;
        float ev = e1s[il];
        float m = -1e30f, l = 0.f;
        for (int j = jt; j < 2048; j += 4) {
            float x = ev + e2s[j];
            x = (x >= 0.f) ? x : 0.2f * x;
            if (x > m) { l = l * __expf(m - x) + 1.0f; m = x; }
            else       { l += __expf(x - m); }
        }
        pm[t] = m; pl[t] = l;
        __syncthreads();
        if (t < 64) {
            float M = pm[t], L = pl[t];
            #pragma unroll
            for (int g2 = 1; g2 < 4; g2++) {
                float m2 = pm[g2 * 64 + t], l2 = pl[g2 * 64 + t];
                if (m2 > M) { L = L * __expf(M - m2) + l2; M = m2; }
                else        { L += l2 * __expf(m2 - M); }
            }
            mS[t] = M; lSinv[t] = 1.0f / L;
        }
        __syncthreads();
    }

    f32x4 acc[4][2];
    #pragma unroll
    for (int a = 0; a < 4; a++)
        #pragma unroll
        for (int b = 0; b < 2; b++) acc[a][b] = (f32x4){0.f, 0.f, 0.f, 0.f};

    for (int j0 = 0; j0 < 2048; j0 += 128) {
        // stage hgT tile: Hs[d][j]  (d=128 rows, 128 j)
        for (int idx = t; idx < 2048; idx += 256) {
            int d = idx >> 4, seg = idx & 15;
            *(bf16x8*)&Hs[d * 136 + seg * 8] =
                *(const bf16x8*)&hgT[(size_t)(h * 128 + d) * 2048 + j0 + seg * 8];
        }
        // compute P tile: Ps[i][j] = exp(lrelu(e1+e2) - m_i) as bf16
        for (int idx = t; idx < 1024; idx += 256) {
            int i = idx >> 4, jg = idx & 15;
            float ei = e1s[i], mi = mS[i];
            bf16x8 pv;
            #pragma unroll
            for (int u = 0; u < 8; u++) {
                float x = ei + e2s[j0 + jg * 8 + u];
                x = (x >= 0.f) ? x : 0.2f * x;
                pv[u] = (bf16_t)__expf(x - mi);
            }
            *(bf16x8*)&Ps[i * 136 + jg * 8] = pv;
        }
        __syncthreads();
        #pragma unroll
        for (int kb = 0; kb < 4; kb++) {
            bf16x8 af[4], bf2[2];
            #pragma unroll
            for (int fn = 0; fn < 4; fn++)
                af[fn] = *(bf16x8*)&Ps[(fn * 16 + lr) * 136 + kb * 32 + q * 8];
            #pragma unroll
            for (int fm = 0; fm < 2; fm++)
                bf2[fm] = *(bf16x8*)&Hs[(wm + fm * 16 + lr) * 136 + kb * 32 + q * 8];
            #pragma unroll
            for (int fn = 0; fn < 4; fn++)
                #pragma unroll
                for (int fm = 0; fm < 2; fm++)
                    acc[fn][fm] = __builtin_amdgcn_mfma_f32_16x16x32_bf16(
                        af[fn], bf2[fm], acc[fn][fm], 0, 0, 0);
        }
        __syncthreads();
    }

    #pragma unroll
    for (int fn = 0; fn < 4; fn++) {
        #pragma unroll
        for (int r = 0; r < 4; r++) {
            int il = fn * 16 + q * 4 + r;
            int i = i0 + il;
            float inv = lSinv[il];
            #pragma unroll
            for (int fm = 0; fm < 2; fm++) {
                int col = h * 128 + wm + fm * 16 + lr;
                float v = acc[fn][fm][r] * inv;
                v = (v > 0.f) ? v : (expf(v) - 1.0f);
                size_t off = (size_t)i * 1024 + col;
                outp[off] = v + feat[off];
            }
        }
    }
}

// ---------------------------------------------------------------------------
extern "C" void kernel_launch(void* const* d_in, const int* in_sizes, int n_in,
                              void* d_out, int out_size, void* d_ws, size_t ws_size,
                              hipStream_t stream)
{
    const float* feat = (const float*)d_in[0];
    const float *cw[5], *cb[5];
    if (in_sizes[2] == 1024) {
        for (int i = 0; i < 5; i++) { cw[i] = (const float*)d_in[1 + 2*i]; cb[i] = (const float*)d_in[2 + 2*i]; }
    } else {
        for (int i = 0; i < 5; i++) { cw[i] = (const float*)d_in[1 + i];   cb[i] = (const float*)d_in[6 + i]; }
    }
    const float* fp_w = (const float*)d_in[11];
    const float* fp_b = (const float*)d_in[12];
    const float* ln_g = (const float*)d_in[13];
    const float* ln_b = (const float*)d_in[14];
    const float* wq = (const float*)d_in[15]; const float* bq = (const float*)d_in[16];
    const float* wk = (const float*)d_in[17]; const float* bk = (const float*)d_in[18];
    const float* wv = (const float*)d_in[19]; const float* bv = (const float*)d_in[20];
    const float* wo = (const float*)d_in[21]; const float* bo = (const float*)d_in[22];
    const float* gat_w = (const float*)d_in[23]; const float* gat_b = (const float*)d_in[24];
    const float* ga1 = (const float*)d_in[25]; const float* ga2 = (const float*)d_in[26];
    float* outp = (float*)d_out;

    // ---- workspace layout (~118 MiB, same as round 4) ----
    char* wsb = (char*)d_ws;
    bf16_t* xb    = (bf16_t*)(wsb);                     //  4,194,304
    bf16_t* msb   = (bf16_t*)(wsb + 4194304);           // 20,971,520
    bf16_t* wcb   = (bf16_t*)(wsb + 25165824);          // 73,400,320
    float*  zf    = (float*) (wsb + 98566144);          //  8,388,608
    bf16_t* zb    = (bf16_t*)(wsb + 106954752);         //  4,194,304
    bf16_t* qb    = (bf16_t*)(wsb + 111149056);         //  4,194,304
    bf16_t* kb    = (bf16_t*)(wsb + 115343360);         //  4,194,304
    bf16_t* vb    = (bf16_t*)(wsb + 119537664);         //  4,194,304
    float*  cball = (float*) (wsb + 123731968);         //     20,480
    float*  e1t   = (float*) (wsb + 123752448);         //     65,536
    float*  e2t   = (float*) (wsb + 123817984);         //     65,536
    // aliases (stream-ordered reuse):
    bf16_t* fpwb = wcb;                 // wcb dead after conv GEMM
    bf16_t* wqb  = wcb + 5242880;
    bf16_t* wkb  = wqb + 1048576;
    bf16_t* wvb  = wkb + 1048576;
    bf16_t* wob  = wvb + 1048576;
    bf16_t* gwb  = wob + 1048576;
    bf16_t* ctxb = qb;                  // attn reads its own q rows first
    bf16_t* attb = kb;                  // kb dead after attn
    float*  hgb  = zf;                  // zf dead after ln_gelu
    bf16_t* hgtb = msb;                 // msb dead after fusion GEMM

    const dim3 blk(256);

    // 1) conversions + conv weight reorder
    cvt_f32_bf16<<<dim3(2048), blk, 0, stream>>>(feat, xb, 524288);
    reorder_convw<<<dim3(20480), blk, 0, stream>>>(cw[0], cw[1], cw[2], cw[3], cw[4], wcb);
    gather_bias<<<dim3(20), blk, 0, stream>>>(cb[0], cb[1], cb[2], cb[3], cb[4], cball);

    // 2) all 5 dilated convs, one MFMA launch -> msb (bf16, ld 5120)
    mfma_gemm<true, true><<<dim3(16, 8, 5), blk, 0, stream>>>(
        xb, wcb, cball, msb, 1024, 1024, 1024, 5120, 0);

    // 3) remaining weight conversions
    cvt_f32_bf16<<<dim3(5120), blk, 0, stream>>>(fp_w, fpwb, 1310720);
    cvt_f32_bf16<<<dim3(1024), blk, 0, stream>>>(wq, wqb, 262144);
    cvt_f32_bf16<<<dim3(1024), blk, 0, stream>>>(wk, wkb, 262144);
    cvt_f32_bf16<<<dim3(1024), blk, 0, stream>>>(wv, wvb, 262144);
    cvt_f32_bf16<<<dim3(1024), blk, 0, stream>>>(wo, wob, 262144);
    cvt_f32_bf16<<<dim3(1024), blk, 0, stream>>>(gat_w, gwb, 262144);

    // 4) fusion projection -> zf (fp32)
    mfma_gemm<false, false><<<dim3(16, 8), blk, 0, stream>>>(
        msb, fpwb, fp_b, zf, 5120, 5120, 5120, 1024, 0);

    // 5) LN + GELU -> zf (fp32) and zb (bf16)
    ln_gelu<<<dim3(2048), blk, 0, stream>>>(zf, zb, ln_g, ln_b);

    // 6) QKV projections -> bf16
    mfma_gemm<false, true><<<dim3(16, 8), blk, 0, stream>>>(zb, wqb, bq, qb, 1024, 1024, 1024, 1024, 0);
    mfma_gemm<false, true><<<dim3(16, 8), blk, 0, stream>>>(zb, wkb, bk, kb, 1024, 1024, 1024, 1024, 0);
    mfma_gemm<false, true><<<dim3(16, 8), blk, 0, stream>>>(zb, wvb, bv, vb, 1024, 1024, 1024, 1024, 0);

    // 7) attention -> ctxb (bf16)
    attn_kernel<<<dim3(8, 16, 8), blk, 0, stream>>>(qb, kb, vb, ctxb);

    // 8) output projection -> attb (bf16)
    mfma_gemm<false, true><<<dim3(16, 8), blk, 0, stream>>>(ctxb, wob, bo, attb, 1024, 1024, 1024, 1024, 0);

    // 9) GAT projection -> hgb (fp32)
    mfma_gemm<false, false><<<dim3(16, 8), blk, 0, stream>>>(attb, gwb, gat_b, hgb, 1024, 1024, 1024, 1024, 0);

    // 10) GAT: transpose hg, logits, fused softmax-aggregate (MFMA)
    transpose_hg<<<dim3(64, 32), blk, 0, stream>>>(hgb, hgtb);
    gat_e<<<dim3(64), blk, 0, stream>>>(hgb, ga1, ga2, e1t, e2t);
    gat_agg_mfma<<<dim3(32, 8), blk, 0, stream>>>(hgtb, e1t, e2t, feat, outp);
}

// Round 6
// 1089.568 us; speedup vs baseline: 5.3017x; 1.0795x over previous
//
#include <hip/hip_runtime.h>
#include <hip/hip_bf16.h>

typedef __bf16 bf16_t;
typedef bf16_t bf16x8 __attribute__((ext_vector_type(8)));
typedef bf16_t bf16x4v __attribute__((ext_vector_type(4)));
typedef float f32x4 __attribute__((ext_vector_type(4)));

// async 16B global->LDS (direct, no VGPR round trip)
__device__ __forceinline__ void gll16(const bf16_t* g, bf16_t* l) {
    __builtin_amdgcn_global_load_lds(
        (const __attribute__((address_space(1))) unsigned int*)g,
        (__attribute__((address_space(3))) unsigned int*)l, 16, 0, 0);
}

// ---------------------------------------------------------------------------
// fp32 -> bf16 elementwise (n multiple of 4)
// ---------------------------------------------------------------------------
__global__ __launch_bounds__(256)
void cvt_f32_bf16(const float* __restrict__ in, bf16_t* __restrict__ out, int n4)
{
    int i = blockIdx.x * 256 + threadIdx.x;
    if (i < n4) {
        float4 v = ((const float4*)in)[i];
        bf16x4v o = { (bf16_t)v.x, (bf16_t)v.y, (bf16_t)v.z, (bf16_t)v.w };
        *(bf16x4v*)&out[i * 4] = o;
    }
}

// ---------------------------------------------------------------------------
// Reorder conv weights (O,C,7) fp32 -> bf16 planes [(i*7+kk)][o][c]
// ---------------------------------------------------------------------------
__global__ __launch_bounds__(256)
void reorder_convw(const float* w0, const float* w1, const float* w2,
                   const float* w3, const float* w4, bf16_t* __restrict__ out)
{
    int gid = blockIdx.x * 256 + threadIdx.x;       // < 5*1024*1024
    int i = gid >> 20, rem = gid & 1048575;
    int o = rem >> 10, c = rem & 1023;
    const float* ws[5] = {w0, w1, w2, w3, w4};
    const float* src = ws[i] + (size_t)o * 7168 + c * 7;
    #pragma unroll
    for (int kk = 0; kk < 7; kk++)
        out[((size_t)(i * 7 + kk) << 20) + (o << 10) + c] = (bf16_t)src[kk];
}

__global__ __launch_bounds__(256)
void gather_bias(const float* b0, const float* b1, const float* b2,
                 const float* b3, const float* b4, float* __restrict__ out,
                 bf16_t* __restrict__ zp)
{
    int idx = blockIdx.x * 256 + threadIdx.x;       // < 5120
    if (blockIdx.x == 0 && threadIdx.x < 32) zp[threadIdx.x] = (bf16_t)0.0f;
    const float* bs[5] = {b0, b1, b2, b3, b4};
    out[idx] = bs[idx >> 10][idx & 1023];
}

// ---------------------------------------------------------------------------
// bf16 MFMA NT GEMM: out[n, m] = sum_k A[n,k]*B[m,k] + bias[oc0+m]
// Tile 128x128, BK=32, 4 waves (2x2 of 64x64), 16x16x32 MFMA.
// Staging: global_load_lds 16B direct to unpadded LDS [row][32].
// Grid: x = m-tiles (conv: conv_i*8+mt, so XCD = mt -> B-tile L2 locality),
//       y = n-tiles. CONV loops 7 taps with shifted A rows; OOB lanes load
//       from a 64B zero page.
// ---------------------------------------------------------------------------
template<bool CONV, bool OUT_BF16>
__global__ __launch_bounds__(256)
void mfma_gemm(const bf16_t* __restrict__ A, const bf16_t* __restrict__ Bw,
               const float* __restrict__ bias, void* __restrict__ outv,
               const bf16_t* __restrict__ zp,
               int Kd, int lda, int ldb, int ldo, int out_col0)
{
    __shared__ __align__(16) bf16_t As[128 * 32];
    __shared__ __align__(16) bf16_t Bs[128 * 32];
    const int t = threadIdx.x;
    const int lane = t & 63, wave = t >> 6;
    const int wn = (wave & 1) * 64, wm = (wave >> 1) * 64;
    const int q = lane >> 4, lr = lane & 15;
    const int mt = CONV ? (blockIdx.x & 7) : blockIdx.x;
    const int conv_i = CONV ? (blockIdx.x >> 3) : 0;
    const int m0 = mt * 128, n0 = blockIdx.y * 128;
    const int srow = lane >> 2, sseg = lane & 3;   // staging row/16B-seg

    f32x4 acc[4][4];
    #pragma unroll
    for (int a = 0; a < 4; a++)
        #pragma unroll
        for (int b = 0; b < 4; b++) acc[a][b] = (f32x4){0.f, 0.f, 0.f, 0.f};

    const int taps = CONV ? 7 : 1;
    for (int kk = 0; kk < taps; kk++) {
        const bf16_t* Bp = CONV ? (Bw + ((size_t)(conv_i * 7 + kk) << 20)) : Bw;
        const int shift = CONV ? ((kk - 3) << conv_i) : 0;
        for (int k0 = 0; k0 < Kd; k0 += 32) {
            #pragma unroll
            for (int p = 0; p < 2; p++) {
                const int slab = p * 64 + wave * 16;     // 16-row slab base
                const int rr = slab + srow;
                // A (with conv temporal shift, zero page when OOB)
                const bf16_t* ga;
                if (CONV) {
                    int n = n0 + rr;
                    int tg = (n & 255) + shift;
                    ga = ((unsigned)tg < 256u)
                       ? A + (size_t)((n & ~255) + tg) * lda + k0 + sseg * 8
                       : zp + sseg * 8;
                } else {
                    ga = A + (size_t)(n0 + rr) * lda + k0 + sseg * 8;
                }
                gll16(ga, &As[slab * 32]);
                // B
                gll16(Bp + (size_t)(m0 + rr) * ldb + k0 + sseg * 8, &Bs[slab * 32]);
            }
            __syncthreads();    // drains vmcnt -> LDS valid
            bf16x8 af[4], bfv[4];
            #pragma unroll
            for (int f = 0; f < 4; f++) {
                af[f]  = *(bf16x8*)&As[(wn + f * 16 + lr) * 32 + q * 8];
                bfv[f] = *(bf16x8*)&Bs[(wm + f * 16 + lr) * 32 + q * 8];
            }
            #pragma unroll
            for (int fn = 0; fn < 4; fn++)
                #pragma unroll
                for (int fm = 0; fm < 4; fm++)
                    acc[fn][fm] = __builtin_amdgcn_mfma_f32_16x16x32_bf16(
                        af[fn], bfv[fm], acc[fn][fm], 0, 0, 0);
            __syncthreads();
        }
    }

    const int oc0 = CONV ? (conv_i << 10) : out_col0;
    #pragma unroll
    for (int fn = 0; fn < 4; fn++) {
        #pragma unroll
        for (int r = 0; r < 4; r++) {
            int n = n0 + wn + fn * 16 + q * 4 + r;
            #pragma unroll
            for (int fm = 0; fm < 4; fm++) {
                int m = m0 + wm + fm * 16 + lr;
                float v = acc[fn][fm][r];
                if (bias) v += bias[oc0 + m];
                if (OUT_BF16)
                    ((bf16_t*)outv)[(size_t)n * ldo + oc0 + m] = (bf16_t)v;
                else
                    ((float*)outv)[(size_t)n * ldo + oc0 + m] = v;
            }
        }
    }
}

// ---------------------------------------------------------------------------
// LayerNorm (eps 1e-5) + exact GELU, in place on z (fp32) + bf16 copy zb.
// ---------------------------------------------------------------------------
__global__ __launch_bounds__(256)
void ln_gelu(float* __restrict__ z, bf16_t* __restrict__ zb,
             const float* __restrict__ g, const float* __restrict__ b)
{
    __shared__ float r1[256], r2[256];
    const int n = blockIdx.x, t = threadIdx.x;
    float* row = z + (size_t)n * 1024;
    float x[4], s = 0.f, s2 = 0.f;
    #pragma unroll
    for (int u = 0; u < 4; u++) {
        x[u] = row[t + u * 256];
        s += x[u]; s2 += x[u] * x[u];
    }
    r1[t] = s; r2[t] = s2;
    __syncthreads();
    for (int off = 128; off > 0; off >>= 1) {
        if (t < off) { r1[t] += r1[t + off]; r2[t] += r2[t + off]; }
        __syncthreads();
    }
    const float mu  = r1[0] * (1.0f / 1024.0f);
    const float var = r2[0] * (1.0f / 1024.0f) - mu * mu;
    const float rstd = rsqrtf(var + 1e-5f);
    #pragma unroll
    for (int u = 0; u < 4; u++) {
        int c = t + u * 256;
        float y = (x[u] - mu) * rstd * g[c] + b[c];
        float gv = 0.5f * y * (1.0f + erff(y * 0.70710678118654752f));
        row[c] = gv;
        zb[(size_t)n * 1024 + c] = (bf16_t)gv;
    }
}

// ---------------------------------------------------------------------------
// MHA core (bf16 q/k/v in, bf16 ctx out), fp32 math.
// ---------------------------------------------------------------------------
__global__ __launch_bounds__(256)
void attn_kernel(const bf16_t* __restrict__ q, const bf16_t* __restrict__ k,
                 const bf16_t* __restrict__ v, bf16_t* __restrict__ ctx)
{
    const int it = blockIdx.x, h = blockIdx.y, bb = blockIdx.z;
    const int i0 = it * 32;
    const size_t base = (size_t)bb * 256 * 1024 + h * 64;
    __shared__ float qs[32][64];
    __shared__ float ks[32][64];
    __shared__ float sc[32][257];
    const int t = threadIdx.x;

    for (int idx = t; idx < 32 * 64; idx += 256) {
        int r = idx >> 6, c = idx & 63;
        qs[r][c] = (float)q[base + (size_t)(i0 + r) * 1024 + c];
    }
    __syncthreads();
    for (int jt = 0; jt < 8; jt++) {
        for (int idx = t; idx < 32 * 64; idx += 256) {
            int r = idx >> 6, c = idx & 63;
            ks[r][c] = (float)k[base + (size_t)(jt * 32 + r) * 1024 + c];
        }
        __syncthreads();
        #pragma unroll
        for (int u = 0; u < 4; u++) {
            int p = t * 4 + u;
            int i = p >> 5, j = p & 31;
            float s = 0.f;
            #pragma unroll 8
            for (int d = 0; d < 64; d++) s += qs[i][d] * ks[j][d];
            sc[i][jt * 32 + j] = s * 0.125f;
        }
        __syncthreads();
    }
    if (t < 32) {
        float m = -1e30f;
        for (int j = 0; j < 256; j++) m = fmaxf(m, sc[t][j]);
        float l = 0.f;
        for (int j = 0; j < 256; j++) { float p = expf(sc[t][j] - m); sc[t][j] = p; l += p; }
        float inv = 1.0f / l;
        for (int j = 0; j < 256; j++) sc[t][j] *= inv;
    }
    __syncthreads();
    const int d = t & 63, ig = t >> 6;
    float acc[8] = {};
    for (int j = 0; j < 256; j++) {
        float vv = (float)v[base + (size_t)j * 1024 + d];
        #pragma unroll
        for (int u = 0; u < 8; u++) acc[u] += sc[ig + u * 4][j] * vv;
    }
    #pragma unroll
    for (int u = 0; u < 8; u++)
        ctx[base + (size_t)(i0 + ig + u * 4) * 1024 + d] = (bf16_t)acc[u];
}

// ---------------------------------------------------------------------------
// GAT logits, TRANSPOSED out: e1t[h][n] = hg[n,h,:].a1 ; e2t likewise.
// ---------------------------------------------------------------------------
__global__ __launch_bounds__(256)
void gat_e(const float* __restrict__ hg, const float* __restrict__ a1,
           const float* __restrict__ a2, float* __restrict__ e1t,
           float* __restrict__ e2t)
{
    int id = blockIdx.x * 256 + threadIdx.x;  // < 16384
    int h = id >> 11, n = id & 2047;
    const float* hr = hg + (size_t)n * 1024 + h * 128;
    float s1 = 0.f, s2 = 0.f;
    for (int d = 0; d < 128; d++) {
        float x = hr[d];
        s1 += x * a1[d];
        s2 += x * a2[d];
    }
    e1t[id] = s1; e2t[id] = s2;
}

// ---------------------------------------------------------------------------
// Transpose hg (2048 x 1024, fp32) -> hgT (1024 x 2048, bf16), 32x32 tiles.
// ---------------------------------------------------------------------------
__global__ __launch_bounds__(256)
void transpose_hg(const float* __restrict__ in, bf16_t* __restrict__ out)
{
    __shared__ float tile[32][33];
    const int t = threadIdx.x;
    const int j0 = blockIdx.x * 32, c0 = blockIdx.y * 32;
    {
        int jl = t >> 3, cl = (t & 7) * 4;
        float4 v = *(const float4*)(in + (size_t)(j0 + jl) * 1024 + c0 + cl);
        tile[jl][cl] = v.x; tile[jl][cl + 1] = v.y;
        tile[jl][cl + 2] = v.z; tile[jl][cl + 3] = v.w;
    }
    __syncthreads();
    {
        int cl = t >> 3, jl = (t & 7) * 4;
        bf16x4v o = { (bf16_t)tile[jl][cl], (bf16_t)tile[jl + 1][cl],
                      (bf16_t)tile[jl + 2][cl], (bf16_t)tile[jl + 3][cl] };
        *(bf16x4v*)&out[(size_t)(c0 + cl) * 2048 + j0 + jl] = o;
    }
}

// ---------------------------------------------------------------------------
// Fused GAT softmax-aggregate via MFMA.  Grid (32, 8) x 256.
// ---------------------------------------------------------------------------
__global__ __launch_bounds__(256)
void gat_agg_mfma(const bf16_t* __restrict__ hgT, const float* __restrict__ e1t,
                  const float* __restrict__ e2t, const float* __restrict__ feat,
                  float* __restrict__ outp)
{
    const int it = blockIdx.x, h = blockIdx.y;
    const int i0 = it * 64;
    __shared__ float e2s[2048];
    __shared__ float e1s[64], mS[64], lSinv[64];
    __shared__ float pm[256], pl[256];
    __shared__ __align__(16) bf16_t Ps[64 * 136];
    __shared__ __align__(16) bf16_t Hs[128 * 136];
    const int t = threadIdx.x;
    const int lane = t & 63, wave = t >> 6;
    const int q = lane >> 4, lr = lane & 15;
    const int wm = wave * 32;

    for (int idx = t; idx < 2048; idx += 256) e2s[idx] = e2t[h * 2048 + idx];
    if (t < 64) e1s[t] = e1t[h * 2048 + i0 + t];
    __syncthreads();

    {   // pass 1: online max/denominator per row i (4 j-groups)
        int il = t & 63, jt = t >> 6;
        float ev = e1s[il];
        float m = -1e30f, l = 0.f;
        for (int j = jt; j < 2048; j += 4) {
            float x = ev + e2s[j];
            x = (x >= 0.f) ? x : 0.2f * x;
            if (x > m) { l = l * __expf(m - x) + 1.0f; m = x; }
            else       { l += __expf(x - m); }
        }
        pm[t] = m; pl[t] = l;
        __syncthreads();
        if (t < 64) {
            float M = pm[t], L = pl[t];
            #pragma unroll
            for (int g2 = 1; g2 < 4; g2++) {
                float m2 = pm[g2 * 64 + t], l2 = pl[g2 * 64 + t];
                if (m2 > M) { L = L * __expf(M - m2) + l2; M = m2; }
                else        { L += l2 * __expf(m2 - M); }
            }
            mS[t] = M; lSinv[t] = 1.0f / L;
        }
        __syncthreads();
    }

    f32x4 acc[4][2];
    #pragma unroll
    for (int a = 0; a < 4; a++)
        #pragma unroll
        for (int b = 0; b < 2; b++) acc[a][b] = (f32x4){0.f, 0.f, 0.f, 0.f};

    for (int j0 = 0; j0 < 2048; j0 += 128) {
        for (int idx = t; idx < 2048; idx += 256) {
            int d = idx >> 4, seg = idx & 15;
            *(bf16x8*)&Hs[d * 136 + seg * 8] =
                *(const bf16x8*)&hgT[(size_t)(h * 128 + d) * 2048 + j0 + seg * 8];
        }
        for (int idx = t; idx < 1024; idx += 256) {
            int i = idx >> 4, jg = idx & 15;
            float ei = e1s[i], mi = mS[i];
            bf16x8 pv;
            #pragma unroll
            for (int u = 0; u < 8; u++) {
                float x = ei + e2s[j0 + jg * 8 + u];
                x = (x >= 0.f) ? x : 0.2f * x;
                pv[u] = (bf16_t)__expf(x - mi);
            }
            *(bf16x8*)&Ps[i * 136 + jg * 8] = pv;
        }
        __syncthreads();
        #pragma unroll
        for (int kb = 0; kb < 4; kb++) {
            bf16x8 af[4], bf2[2];
            #pragma unroll
            for (int fn = 0; fn < 4; fn++)
                af[fn] = *(bf16x8*)&Ps[(fn * 16 + lr) * 136 + kb * 32 + q * 8];
            #pragma unroll
            for (int fm = 0; fm < 2; fm++)
                bf2[fm] = *(bf16x8*)&Hs[(wm + fm * 16 + lr) * 136 + kb * 32 + q * 8];
            #pragma unroll
            for (int fn = 0; fn < 4; fn++)
                #pragma unroll
                for (int fm = 0; fm < 2; fm++)
                    acc[fn][fm] = __builtin_amdgcn_mfma_f32_16x16x32_bf16(
                        af[fn], bf2[fm], acc[fn][fm], 0, 0, 0);
        }
        __syncthreads();
    }

    #pragma unroll
    for (int fn = 0; fn < 4; fn++) {
        #pragma unroll
        for (int r = 0; r < 4; r++) {
            int il = fn * 16 + q * 4 + r;
            int i = i0 + il;
            float inv = lSinv[il];
            #pragma unroll
            for (int fm = 0; fm < 2; fm++) {
                int col = h * 128 + wm + fm * 16 + lr;
                float v = acc[fn][fm][r] * inv;
                v = (v > 0.f) ? v : (expf(v) - 1.0f);
                size_t off = (size_t)i * 1024 + col;
                outp[off] = v + feat[off];
            }
        }
    }
}

// ---------------------------------------------------------------------------
extern "C" void kernel_launch(void* const* d_in, const int* in_sizes, int n_in,
                              void* d_out, int out_size, void* d_ws, size_t ws_size,
                              hipStream_t stream)
{
    const float* feat = (const float*)d_in[0];
    const float *cw[5], *cb[5];
    if (in_sizes[2] == 1024) {
        for (int i = 0; i < 5; i++) { cw[i] = (const float*)d_in[1 + 2*i]; cb[i] = (const float*)d_in[2 + 2*i]; }
    } else {
        for (int i = 0; i < 5; i++) { cw[i] = (const float*)d_in[1 + i];   cb[i] = (const float*)d_in[6 + i]; }
    }
    const float* fp_w = (const float*)d_in[11];
    const float* fp_b = (const float*)d_in[12];
    const float* ln_g = (const float*)d_in[13];
    const float* ln_b = (const float*)d_in[14];
    const float* wq = (const float*)d_in[15]; const float* bq = (const float*)d_in[16];
    const float* wk = (const float*)d_in[17]; const float* bk = (const float*)d_in[18];
    const float* wv = (const float*)d_in[19]; const float* bv = (const float*)d_in[20];
    const float* wo = (const float*)d_in[21]; const float* bo = (const float*)d_in[22];
    const float* gat_w = (const float*)d_in[23]; const float* gat_b = (const float*)d_in[24];
    const float* ga1 = (const float*)d_in[25]; const float* ga2 = (const float*)d_in[26];
    float* outp = (float*)d_out;

    // ---- workspace layout (~118 MiB) ----
    char* wsb = (char*)d_ws;
    bf16_t* xb    = (bf16_t*)(wsb);                     //  4,194,304
    bf16_t* msb   = (bf16_t*)(wsb + 4194304);           // 20,971,520
    bf16_t* wcb   = (bf16_t*)(wsb + 25165824);          // 73,400,320
    float*  zf    = (float*) (wsb + 98566144);          //  8,388,608
    bf16_t* zb    = (bf16_t*)(wsb + 106954752);         //  4,194,304
    bf16_t* qb    = (bf16_t*)(wsb + 111149056);         //  4,194,304
    bf16_t* kb    = (bf16_t*)(wsb + 115343360);         //  4,194,304
    bf16_t* vb    = (bf16_t*)(wsb + 119537664);         //  4,194,304
    float*  cball = (float*) (wsb + 123731968);         //     20,480
    float*  e1t   = (float*) (wsb + 123752448);         //     65,536
    float*  e2t   = (float*) (wsb + 123817984);         //     65,536
    bf16_t* zpage = (bf16_t*)(wsb + 123883520);         //         64
    // aliases (stream-ordered reuse):
    bf16_t* fpwb = wcb;                 // wcb dead after conv GEMM
    bf16_t* wqb  = wcb + 5242880;
    bf16_t* wkb  = wqb + 1048576;
    bf16_t* wvb  = wkb + 1048576;
    bf16_t* wob  = wvb + 1048576;
    bf16_t* gwb  = wob + 1048576;
    bf16_t* ctxb = qb;                  // attn reads its own q rows first
    bf16_t* attb = kb;                  // kb dead after attn
    float*  hgb  = zf;                  // zf dead after ln_gelu
    bf16_t* hgtb = msb;                 // msb dead after fusion GEMM

    const dim3 blk(256);

    // 1) conversions + conv weight reorder (+ zero page)
    cvt_f32_bf16<<<dim3(2048), blk, 0, stream>>>(feat, xb, 524288);
    reorder_convw<<<dim3(20480), blk, 0, stream>>>(cw[0], cw[1], cw[2], cw[3], cw[4], wcb);
    gather_bias<<<dim3(20), blk, 0, stream>>>(cb[0], cb[1], cb[2], cb[3], cb[4], cball, zpage);

    // 2) all 5 dilated convs, one MFMA launch -> msb (bf16, ld 5120)
    //    grid x = conv_i*8 + m-tile  (XCD = m-tile for B-tile L2 locality)
    mfma_gemm<true, true><<<dim3(40, 16), blk, 0, stream>>>(
        xb, wcb, cball, msb, zpage, 1024, 1024, 1024, 5120, 0);

    // 3) remaining weight conversions
    cvt_f32_bf16<<<dim3(5120), blk, 0, stream>>>(fp_w, fpwb, 1310720);
    cvt_f32_bf16<<<dim3(1024), blk, 0, stream>>>(wq, wqb, 262144);
    cvt_f32_bf16<<<dim3(1024), blk, 0, stream>>>(wk, wkb, 262144);
    cvt_f32_bf16<<<dim3(1024), blk, 0, stream>>>(wv, wvb, 262144);
    cvt_f32_bf16<<<dim3(1024), blk, 0, stream>>>(wo, wob, 262144);
    cvt_f32_bf16<<<dim3(1024), blk, 0, stream>>>(gat_w, gwb, 262144);

    // 4) fusion projection -> zf (fp32)
    mfma_gemm<false, false><<<dim3(8, 16), blk, 0, stream>>>(
        msb, fpwb, fp_b, zf, zpage, 5120, 5120, 5120, 1024, 0);

    // 5) LN + GELU -> zf (fp32) and zb (bf16)
    ln_gelu<<<dim3(2048), blk, 0, stream>>>(zf, zb, ln_g, ln_b);

    // 6) QKV projections -> bf16
    mfma_gemm<false, true><<<dim3(8, 16), blk, 0, stream>>>(zb, wqb, bq, qb, zpage, 1024, 1024, 1024, 1024, 0);
    mfma_gemm<false, true><<<dim3(8, 16), blk, 0, stream>>>(zb, wkb, bk, kb, zpage, 1024, 1024, 1024, 1024, 0);
    mfma_gemm<false, true><<<dim3(8, 16), blk, 0, stream>>>(zb, wvb, bv, vb, zpage, 1024, 1024, 1024, 1024, 0);

    // 7) attention -> ctxb (bf16)
    attn_kernel<<<dim3(8, 16, 8), blk, 0, stream>>>(qb, kb, vb, ctxb);

    // 8) output projection -> attb (bf16)
    mfma_gemm<false, true><<<dim3(8, 16), blk, 0, stream>>>(ctxb, wob, bo, attb, zpage, 1024, 1024, 1024, 1024, 0);

    // 9) GAT projection -> hgb (fp32)
    mfma_gemm<false, false><<<dim3(8, 16), blk, 0, stream>>>(attb, gwb, gat_b, hgb, zpage, 1024, 1024, 1024, 1024, 0);

    // 10) GAT: transpose hg, logits, fused softmax-aggregate (MFMA)
    transpose_hg<<<dim3(64, 32), blk, 0, stream>>>(hgb, hgtb);
    gat_e<<<dim3(64), blk, 0, stream>>>(hgb, ga1, ga2, e1t, e2t);
    gat_agg_mfma<<<dim3(32, 8), blk, 0, stream>>>(hgtb, e1t, e2t, feat, outp);
}